// Round 6
// baseline (251.421 us; speedup 1.0000x reference)
//
#include <hip/hip_runtime.h>
#include <hip/hip_bf16.h>

typedef __bf16 bf16x8 __attribute__((ext_vector_type(8)));
typedef __bf16 bf16x4 __attribute__((ext_vector_type(4)));
typedef float  f32x4  __attribute__((ext_vector_type(4)));

#define MFMA_BF16(a, b, c) __builtin_amdgcn_mfma_f32_16x16x32_bf16((a), (b), (c), 0, 0, 0)

#define GLOAD_LDS16(g, l)                                          \
  __builtin_amdgcn_global_load_lds(                                \
      (const __attribute__((address_space(1))) void*)(g),          \
      (__attribute__((address_space(3))) void*)(l), 16, 0, 0)

static constexpr int kDim = 1024;
static constexpr int kHeads = 16;
static constexpr int kB = 4;
static constexpr int kNKV = 1024;

// ---------------------------------------------------------------------------
// fp32 -> bf16 canonicalization (fp32 inputs confirmed r1/r2).
// ---------------------------------------------------------------------------
struct Conv6 {
  const float* src[6];
  __bf16* dst[6];
  int n4[6];
};
__global__ __launch_bounds__(256) void convert6(Conv6 a) {
  const int w = blockIdx.y;
  const float4* __restrict__ s = (const float4*)a.src[w];
  __bf16* __restrict__ d = a.dst[w];
  const int n4 = a.n4[w];
  const int stride = gridDim.x * blockDim.x;
  for (int i = blockIdx.x * blockDim.x + threadIdx.x; i < n4; i += stride) {
    const float4 v = s[i];
    bf16x4 o = {(__bf16)v.x, (__bf16)v.y, (__bf16)v.z, (__bf16)v.w};
    *(bf16x4*)(d + (size_t)i * 4) = o;
  }
}

// ---------------------------------------------------------------------------
// QKV NT-GEMM (unchanged from r5; will optimize with counters once visible).
// ---------------------------------------------------------------------------
struct QKVArgs {
  const __bf16* A[3];
  const __bf16* W[3];
  const float* bias[3];
  const float* rel;
  __bf16* out[3];
};

__global__ __launch_bounds__(256) void qkv_gemm(QKVArgs args) {
  constexpr int K = kDim;
  constexpr int CT_STRIDE = 136;
  __shared__ __bf16 As[128 * 32];
  __shared__ __bf16 Bs[128 * 32];
  __shared__ __bf16 Ct[128 * CT_STRIDE];
  const int z = blockIdx.z;  // 0=Q, 1=K, 2=V
  const __bf16* __restrict__ A = args.A[z];
  const __bf16* __restrict__ W = args.W[z];
  const float* __restrict__ bias = args.bias[z];
  const float* __restrict__ rel = args.rel;
  __bf16* __restrict__ out = args.out[z];

  const int tid = threadIdx.x;
  const int wave = tid >> 6, lane = tid & 63;
  const int lr = lane & 15, quad = lane >> 4;
  const int wm = (wave & 1) << 6, wn = (wave >> 1) << 6;
  const int m0 = blockIdx.y << 7, n0 = blockIdx.x << 7;
  const int bb = m0 >> 10;

  f32x4 acc[4][4] = {};

  for (int k0 = 0; k0 < K; k0 += 32) {
    __syncthreads();
#pragma unroll
    for (int i = 0; i < 2; ++i) {
      const int ch = tid + (i << 8);
      const int row = ch >> 2, col = (ch & 3) << 3;
      GLOAD_LDS16(A + (size_t)(m0 + row) * K + k0 + col, As + ch * 8);
      GLOAD_LDS16(W + (size_t)(n0 + row) * K + k0 + col, Bs + ch * 8);
    }
    __syncthreads();
    bf16x8 afr[4], bfr[4];
#pragma unroll
    for (int mi = 0; mi < 4; ++mi)
      afr[mi] = *(const bf16x8*)&As[(wm + mi * 16 + lr) * 32 + quad * 8];
#pragma unroll
    for (int ni = 0; ni < 4; ++ni)
      bfr[ni] = *(const bf16x8*)&Bs[(wn + ni * 16 + lr) * 32 + quad * 8];
#pragma unroll
    for (int mi = 0; mi < 4; ++mi)
#pragma unroll
      for (int ni = 0; ni < 4; ++ni)
        acc[mi][ni] = MFMA_BF16(afr[mi], bfr[ni], acc[mi][ni]);
  }

#pragma unroll
  for (int mi = 0; mi < 4; ++mi)
#pragma unroll
    for (int ni = 0; ni < 4; ++ni) {
      const int col_l = wn + ni * 16 + lr;
      const float bc = bias[n0 + col_l];
      const f32x4 v = acc[mi][ni];
      const int row0 = wm + mi * 16 + (quad << 2);
      if (z == 2) {
        const f32x4 r4 = *(const f32x4*)(rel + (bb << 10) + ((m0 + row0) & 1023));
        bf16x4 pk;
#pragma unroll
        for (int r = 0; r < 4; ++r) pk[r] = (__bf16)((v[r] + bc) * r4[r]);
        *(bf16x4*)&Ct[col_l * CT_STRIDE + row0] = pk;
      } else if (z == 1) {
        const f32x4 r4 = *(const f32x4*)(rel + (bb << 10) + ((m0 + row0) & 1023));
#pragma unroll
        for (int r = 0; r < 4; ++r)
          Ct[(row0 + r) * CT_STRIDE + col_l] = (__bf16)((v[r] + bc) * r4[r]);
      } else {
#pragma unroll
        for (int r = 0; r < 4; ++r)
          Ct[(row0 + r) * CT_STRIDE + col_l] = (__bf16)(v[r] + bc);
      }
    }
  __syncthreads();

  const int hh0 = n0 >> 6;
  if (z == 2) {
#pragma unroll
    for (int j = 0; j < 8; ++j) {
      const int idx = (j << 8) + tid;
      const int c = idx >> 4, r8 = (idx & 15) << 3;
      const bf16x8 vv = *(const bf16x8*)&Ct[c * CT_STRIDE + r8];
      const int col = n0 + c;
      const int hh = col >> 6, dd = col & 63;
      *(bf16x8*)(out + ((size_t)(bb * kHeads + hh) * 64 + dd) * 1024 +
                 (m0 & 1023) + r8) = vv;
    }
  } else {
#pragma unroll
    for (int j = 0; j < 8; ++j) {
      const int idx = (j << 8) + tid;
      const int r = idx >> 4, c8 = (idx & 15) << 3;
      const bf16x8 vv = *(const bf16x8*)&Ct[r * CT_STRIDE + c8];
      const int hh = hh0 + (c8 >> 6), dd = c8 & 63;
      *(bf16x8*)(out + ((size_t)(bb * kHeads + hh) << 16) +
                 (size_t)((m0 & 1023) + r) * 64 + dd) = vv;
    }
  }
}

// O-projection (unchanged).
__global__ __launch_bounds__(256) void o_gemm(const __bf16* __restrict__ A,
                                              const __bf16* __restrict__ W,
                                              const float* __restrict__ bias,
                                              float* __restrict__ out) {
  constexpr int K = kDim;
  __shared__ __bf16 As[128 * 32];
  __shared__ __bf16 Bs[128 * 32];
  const int tid = threadIdx.x;
  const int wave = tid >> 6, lane = tid & 63;
  const int lr = lane & 15, quad = lane >> 4;
  const int wm = (wave & 1) << 6, wn = (wave >> 1) << 6;
  const int m0 = blockIdx.y << 7, n0 = blockIdx.x << 7;

  f32x4 acc[4][4] = {};
  for (int k0 = 0; k0 < K; k0 += 32) {
    __syncthreads();
#pragma unroll
    for (int i = 0; i < 2; ++i) {
      const int ch = tid + (i << 8);
      const int row = ch >> 2, col = (ch & 3) << 3;
      GLOAD_LDS16(A + (size_t)(m0 + row) * K + k0 + col, As + ch * 8);
      GLOAD_LDS16(W + (size_t)(n0 + row) * K + k0 + col, Bs + ch * 8);
    }
    __syncthreads();
    bf16x8 afr[4], bfr[4];
#pragma unroll
    for (int mi = 0; mi < 4; ++mi)
      afr[mi] = *(const bf16x8*)&As[(wm + mi * 16 + lr) * 32 + quad * 8];
#pragma unroll
    for (int ni = 0; ni < 4; ++ni)
      bfr[ni] = *(const bf16x8*)&Bs[(wn + ni * 16 + lr) * 32 + quad * 8];
#pragma unroll
    for (int mi = 0; mi < 4; ++mi)
#pragma unroll
      for (int ni = 0; ni < 4; ++ni)
        acc[mi][ni] = MFMA_BF16(afr[mi], bfr[ni], acc[mi][ni]);
  }
#pragma unroll
  for (int mi = 0; mi < 4; ++mi)
#pragma unroll
    for (int ni = 0; ni < 4; ++ni) {
      const int col = n0 + wn + ni * 16 + lr;
      const float bc = bias[col];
      const f32x4 v = acc[mi][ni];
#pragma unroll
      for (int r = 0; r < 4; ++r) {
        const int row = m0 + wm + mi * 16 + (quad << 2) + r;
        out[(size_t)row * kDim + col] = v[r] + bc;
      }
    }
}

// ---------------------------------------------------------------------------
// Attention r6: 512 threads (8 waves), 32 q-rows/WG, XCD head clustering.
// Phase 1: wave w does k-tiles w+8i (i<8), both q-halves (ILP 4).
// Phase 3: wave = (d-tile = w&3, kv-half = w>>2) — V rows PARTITIONED (no
// duplicate reads, unlike r4), both q-halves kept (ILP 4). Partial O/L
// reduced pairwise across kv-halves via 16 KB LDS + 1 barrier.
// Occupancy: 2 WG x 8 waves = 16 waves/CU = 4/SIMD (2x r5).
// ---------------------------------------------------------------------------
__global__ __launch_bounds__(512, 4) void attn32(const __bf16* __restrict__ Qb,
                                                 const __bf16* __restrict__ Kb,
                                                 const __bf16* __restrict__ Vb,
                                                 const float* __restrict__ rel,
                                                 __bf16* __restrict__ AO) {
  __shared__ __bf16 S[32 * 1024];  // 64 KB
  __shared__ float Rbuf[4096];     // 16 KB partial O/L exchange
  const int tid = threadIdx.x;
  const int wave = tid >> 6, lane = tid & 63;
  const int lr = lane & 15, quad = lane >> 4;
  // XCD clustering: all 32 WGs of a (b,h) share bid%8 -> same XCD L2.
  const int x = blockIdx.x & 7, g = blockIdx.x >> 3;
  const int hg = x + ((g >> 5) << 3);
  const int b = hg >> 4, h = hg & 15, q0 = (g & 31) << 5;
  const __bf16* Qh = Qb + ((size_t)(b * kHeads + h) << 16);  // [n][64]
  const __bf16* Kh = Kb + ((size_t)(b * kHeads + h) << 16);  // [n][64] (r folded)
  const __bf16* Vh = Vb + ((size_t)(b * kHeads + h) << 16);  // [64][n] (r folded)
  const float* rb = rel + (b << 10);

  // Q as B-fragments: B[n = q-row = lane&15][k = quad*8+j]
  bf16x8 qfrag[2][2];
#pragma unroll
  for (int mt = 0; mt < 2; ++mt) {
    const __bf16* qrow = Qh + (q0 + mt * 16 + lr) * 64 + quad * 8;
    qfrag[mt][0] = *(const bf16x8*)qrow;
    qfrag[mt][1] = *(const bf16x8*)(qrow + 32);
  }

  // Phase 1: D[kv][q] = K.Q^T; p = clip(r)*exp(s*0.125); pipelined K loads.
  // S[q][kv] bf16, chunk-XOR swizzle: addr = q*1024 + ((kv/8 ^ (q&7))*8 + kv%8.
  {
    const __bf16* kp = Kh + ((wave << 4) + lr) * 64 + quad * 8;
    bf16x8 ka0 = *(const bf16x8*)kp;
    bf16x8 ka1 = *(const bf16x8*)(kp + 32);
    f32x4 rcv = *(const f32x4*)(rb + (wave << 4) + (quad << 2));
    for (int i = 0; i < 8; ++i) {
      bf16x8 kn0, kn1;
      f32x4 rn;
      if (i < 7) {
        const int n1 = (((i + 1) << 3) + wave) << 4;
        const __bf16* kq = Kh + (n1 + lr) * 64 + quad * 8;
        kn0 = *(const bf16x8*)kq;
        kn1 = *(const bf16x8*)(kq + 32);
        rn = *(const f32x4*)(rb + n1 + (quad << 2));
      }
      const int n0 = ((i << 3) + wave) << 4;
      const int kvb = n0 + (quad << 2);
      const int cb = kvb >> 3, k7 = kvb & 7;
#pragma unroll
      for (int mt = 0; mt < 2; ++mt) {
        f32x4 acc = {0.f, 0.f, 0.f, 0.f};
        acc = MFMA_BF16(ka0, qfrag[mt][0], acc);
        acc = MFMA_BF16(ka1, qfrag[mt][1], acc);
        const int q = (mt << 4) + lr;  // D col = q-row
        bf16x4 pk;
#pragma unroll
        for (int r = 0; r < 4; ++r)    // D row = quad*4+r = kv
          pk[r] = (__bf16)(fmaxf(rcv[r], 1e-6f) * __expf(acc[r] * 0.125f));
        *(bf16x4*)&S[(q << 10) + ((cb ^ (q & 7)) << 3) + k7] = pk;
      }
      ka0 = kn0; ka1 = kn1; rcv = rn;
    }
  }
  __syncthreads();

  // Phase 3: wave = (dt, kvh); O = P V'^T over kv in [kvh*512, +512).
  bf16x8 ones;
#pragma unroll
  for (int j = 0; j < 8; ++j) ones[j] = (__bf16)1.0f;
  const int dt = wave & 3, kvh = wave >> 2;
  const int d0 = dt << 4;
  const __bf16* vrow = Vh + (size_t)(d0 + lr) * kNKV + (kvh << 9) + (quad << 3);
  const int xr = lr & 7, cbase = kvh << 6;
  f32x4 accO[2] = {{0.f, 0.f, 0.f, 0.f}, {0.f, 0.f, 0.f, 0.f}};
  f32x4 accL[2] = {{0.f, 0.f, 0.f, 0.f}, {0.f, 0.f, 0.f, 0.f}};
  bf16x8 bv = *(const bf16x8*)vrow;
  bf16x8 af[2];
#pragma unroll
  for (int mt = 0; mt < 2; ++mt)
    af[mt] = *(const bf16x8*)&S[(((mt << 4) + lr) << 10) +
                                (((cbase + quad) ^ xr) << 3)];
  for (int kk = 0; kk < 16; ++kk) {
    bf16x8 bvn, afn[2];
    if (kk < 15) {  // prefetch next V chunk + next S fragments
      bvn = *(const bf16x8*)(vrow + ((kk + 1) << 5));
      const int c1 = cbase + ((kk + 1) << 2) + quad;
#pragma unroll
      for (int mt = 0; mt < 2; ++mt)
        afn[mt] = *(const bf16x8*)&S[(((mt << 4) + lr) << 10) + ((c1 ^ xr) << 3)];
    }
#pragma unroll
    for (int mt = 0; mt < 2; ++mt) {
      accO[mt] = MFMA_BF16(af[mt], bv, accO[mt]);
      accL[mt] = MFMA_BF16(af[mt], ones, accL[mt]);
    }
    bv = bvn; af[0] = afn[0]; af[1] = afn[1];
  }

  // Pairwise cross-wave reduce (kvh=1 -> kvh=0) via Rbuf, then epilogue.
  if (kvh == 1) {
#pragma unroll
    for (int mt = 0; mt < 2; ++mt) {
      const int slot = (((dt << 1) | mt) << 8) + (lane << 2);
      *(f32x4*)&Rbuf[slot] = accO[mt];
      *(f32x4*)&Rbuf[2048 + slot] = accL[mt];
    }
  }
  __syncthreads();
  if (kvh == 0) {
    const int dcol = (h << 6) + d0 + lr;
#pragma unroll
    for (int mt = 0; mt < 2; ++mt) {
      const int slot = (((dt << 1) | mt) << 8) + (lane << 2);
      const f32x4 oo = accO[mt] + *(const f32x4*)&Rbuf[slot];
      const f32x4 ll = accL[mt] + *(const f32x4*)&Rbuf[2048 + slot];
      const size_t ob = (size_t)(b << 10) + q0 + (mt << 4);
#pragma unroll
      for (int r = 0; r < 4; ++r)
        AO[(ob + (quad << 2) + r) * kDim + dcol] = (__bf16)(oo[r] / ll[r]);
    }
  }
}

extern "C" void kernel_launch(void* const* d_in, const int* in_sizes, int n_in,
                              void* d_out, int out_size, void* d_ws, size_t ws_size,
                              hipStream_t stream) {
  (void)in_sizes; (void)n_in; (void)out_size; (void)ws_size;
  const float* qf  = (const float*)d_in[0];
  const float* kvf = (const float*)d_in[1];
  const float* rel = (const float*)d_in[2];
  const float* Wq  = (const float*)d_in[3];
  const float* bq  = (const float*)d_in[4];
  const float* Wk  = (const float*)d_in[5];
  const float* bk  = (const float*)d_in[6];
  const float* Wv  = (const float*)d_in[7];
  const float* bv  = (const float*)d_in[8];
  const float* Wo  = (const float*)d_in[9];
  const float* bo  = (const float*)d_in[10];

  const size_t big = (size_t)kB * 1024 * kDim;  // 4M elements
  __bf16* p = (__bf16*)d_ws;
  __bf16* cqf  = p; p += big;
  __bf16* ckvf = p; p += big;
  __bf16* cWq  = p; p += kDim * kDim;
  __bf16* cWk  = p; p += kDim * kDim;
  __bf16* cWv  = p; p += kDim * kDim;
  __bf16* cWo  = p; p += kDim * kDim;
  __bf16* q_buf  = p; p += big;
  __bf16* k_buf  = p; p += big;
  __bf16* vT_buf = p; p += big;
  __bf16* ao_buf = p; p += big;

  Conv6 cv;
  const float* srcs[6] = {qf, kvf, Wq, Wk, Wv, Wo};
  __bf16* dsts[6] = {cqf, ckvf, cWq, cWk, cWv, cWo};
  const int n4s[6] = {(int)(big >> 2), (int)(big >> 2),
                      kDim * kDim / 4, kDim * kDim / 4, kDim * kDim / 4, kDim * kDim / 4};
  for (int i = 0; i < 6; ++i) { cv.src[i] = srcs[i]; cv.dst[i] = dsts[i]; cv.n4[i] = n4s[i]; }
  convert6<<<dim3(256, 6), 256, 0, stream>>>(cv);

  QKVArgs qa;
  qa.A[0] = cqf;  qa.A[1] = ckvf; qa.A[2] = ckvf;
  qa.W[0] = cWq;  qa.W[1] = cWk;  qa.W[2] = cWv;
  qa.bias[0] = bq; qa.bias[1] = bk; qa.bias[2] = bv;
  qa.rel = rel;
  qa.out[0] = q_buf; qa.out[1] = k_buf; qa.out[2] = vT_buf;
  qkv_gemm<<<dim3(kDim / 128, (kB * 1024) / 128, 3), 256, 0, stream>>>(qa);

  attn32<<<kB * kHeads * (1024 / 32), 512, 0, stream>>>(q_buf, k_buf, vT_buf, rel, ao_buf);

  o_gemm<<<dim3(kDim / 128, (kB * 1024) / 128), 256, 0, stream>>>(ao_buf, cWo, bo, (float*)d_out);
}

// Round 7
// 223.768 us; speedup vs baseline: 1.1236x; 1.1236x over previous
//
#include <hip/hip_runtime.h>
#include <hip/hip_bf16.h>

typedef __bf16 bf16x8 __attribute__((ext_vector_type(8)));
typedef __bf16 bf16x4 __attribute__((ext_vector_type(4)));
typedef __bf16 bf16x2 __attribute__((ext_vector_type(2)));
typedef float  f32x4  __attribute__((ext_vector_type(4)));

#define MFMA_BF16(a, b, c) __builtin_amdgcn_mfma_f32_16x16x32_bf16((a), (b), (c), 0, 0, 0)

#define GLOAD_LDS16(g, l)                                          \
  __builtin_amdgcn_global_load_lds(                                \
      (const __attribute__((address_space(1))) void*)(g),          \
      (__attribute__((address_space(3))) void*)(l), 16, 0, 0)

static constexpr int kDim = 1024;
static constexpr int kHeads = 16;
static constexpr int kB = 4;
static constexpr int kNKV = 1024;

// ---------------------------------------------------------------------------
// fp32 -> bf16 canonicalization (fp32 inputs confirmed r1/r2).
// ---------------------------------------------------------------------------
struct Conv6 {
  const float* src[6];
  __bf16* dst[6];
  int n4[6];
};
__global__ __launch_bounds__(256) void convert6(Conv6 a) {
  const int w = blockIdx.y;
  const float4* __restrict__ s = (const float4*)a.src[w];
  __bf16* __restrict__ d = a.dst[w];
  const int n4 = a.n4[w];
  const int stride = gridDim.x * blockDim.x;
  for (int i = blockIdx.x * blockDim.x + threadIdx.x; i < n4; i += stride) {
    const float4 v = s[i];
    bf16x4 o = {(__bf16)v.x, (__bf16)v.y, (__bf16)v.z, (__bf16)v.w};
    *(bf16x4*)(d + (size_t)i * 4) = o;
  }
}

// ---------------------------------------------------------------------------
// QKV NT-GEMM (byte-identical to r6 — no blind edits until counters visible).
// ---------------------------------------------------------------------------
struct QKVArgs {
  const __bf16* A[3];
  const __bf16* W[3];
  const float* bias[3];
  const float* rel;
  __bf16* out[3];
};

__global__ __launch_bounds__(256) void qkv_gemm(QKVArgs args) {
  constexpr int K = kDim;
  constexpr int CT_STRIDE = 136;
  __shared__ __bf16 As[128 * 32];
  __shared__ __bf16 Bs[128 * 32];
  __shared__ __bf16 Ct[128 * CT_STRIDE];
  const int z = blockIdx.z;  // 0=Q, 1=K, 2=V
  const __bf16* __restrict__ A = args.A[z];
  const __bf16* __restrict__ W = args.W[z];
  const float* __restrict__ bias = args.bias[z];
  const float* __restrict__ rel = args.rel;
  __bf16* __restrict__ out = args.out[z];

  const int tid = threadIdx.x;
  const int wave = tid >> 6, lane = tid & 63;
  const int lr = lane & 15, quad = lane >> 4;
  const int wm = (wave & 1) << 6, wn = (wave >> 1) << 6;
  const int m0 = blockIdx.y << 7, n0 = blockIdx.x << 7;
  const int bb = m0 >> 10;

  f32x4 acc[4][4] = {};

  for (int k0 = 0; k0 < K; k0 += 32) {
    __syncthreads();
#pragma unroll
    for (int i = 0; i < 2; ++i) {
      const int ch = tid + (i << 8);
      const int row = ch >> 2, col = (ch & 3) << 3;
      GLOAD_LDS16(A + (size_t)(m0 + row) * K + k0 + col, As + ch * 8);
      GLOAD_LDS16(W + (size_t)(n0 + row) * K + k0 + col, Bs + ch * 8);
    }
    __syncthreads();
    bf16x8 afr[4], bfr[4];
#pragma unroll
    for (int mi = 0; mi < 4; ++mi)
      afr[mi] = *(const bf16x8*)&As[(wm + mi * 16 + lr) * 32 + quad * 8];
#pragma unroll
    for (int ni = 0; ni < 4; ++ni)
      bfr[ni] = *(const bf16x8*)&Bs[(wn + ni * 16 + lr) * 32 + quad * 8];
#pragma unroll
    for (int mi = 0; mi < 4; ++mi)
#pragma unroll
      for (int ni = 0; ni < 4; ++ni)
        acc[mi][ni] = MFMA_BF16(afr[mi], bfr[ni], acc[mi][ni]);
  }

#pragma unroll
  for (int mi = 0; mi < 4; ++mi)
#pragma unroll
    for (int ni = 0; ni < 4; ++ni) {
      const int col_l = wn + ni * 16 + lr;
      const float bc = bias[n0 + col_l];
      const f32x4 v = acc[mi][ni];
      const int row0 = wm + mi * 16 + (quad << 2);
      if (z == 2) {
        const f32x4 r4 = *(const f32x4*)(rel + (bb << 10) + ((m0 + row0) & 1023));
        bf16x4 pk;
#pragma unroll
        for (int r = 0; r < 4; ++r) pk[r] = (__bf16)((v[r] + bc) * r4[r]);
        *(bf16x4*)&Ct[col_l * CT_STRIDE + row0] = pk;
      } else if (z == 1) {
        const f32x4 r4 = *(const f32x4*)(rel + (bb << 10) + ((m0 + row0) & 1023));
#pragma unroll
        for (int r = 0; r < 4; ++r)
          Ct[(row0 + r) * CT_STRIDE + col_l] = (__bf16)((v[r] + bc) * r4[r]);
      } else {
#pragma unroll
        for (int r = 0; r < 4; ++r)
          Ct[(row0 + r) * CT_STRIDE + col_l] = (__bf16)(v[r] + bc);
      }
    }
  __syncthreads();

  const int hh0 = n0 >> 6;
  if (z == 2) {
#pragma unroll
    for (int j = 0; j < 8; ++j) {
      const int idx = (j << 8) + tid;
      const int c = idx >> 4, r8 = (idx & 15) << 3;
      const bf16x8 vv = *(const bf16x8*)&Ct[c * CT_STRIDE + r8];
      const int col = n0 + c;
      const int hh = col >> 6, dd = col & 63;
      *(bf16x8*)(out + ((size_t)(bb * kHeads + hh) * 64 + dd) * 1024 +
                 (m0 & 1023) + r8) = vv;
    }
  } else {
#pragma unroll
    for (int j = 0; j < 8; ++j) {
      const int idx = (j << 8) + tid;
      const int r = idx >> 4, c8 = (idx & 15) << 3;
      const bf16x8 vv = *(const bf16x8*)&Ct[r * CT_STRIDE + c8];
      const int hh = hh0 + (c8 >> 6), dd = c8 & 63;
      *(bf16x8*)(out + ((size_t)(bb * kHeads + hh) << 16) +
                 (size_t)((m0 & 1023) + r) * 64 + dd) = vv;
    }
  }
}

// O-projection (unchanged).
__global__ __launch_bounds__(256) void o_gemm(const __bf16* __restrict__ A,
                                              const __bf16* __restrict__ W,
                                              const float* __restrict__ bias,
                                              float* __restrict__ out) {
  constexpr int K = kDim;
  __shared__ __bf16 As[128 * 32];
  __shared__ __bf16 Bs[128 * 32];
  const int tid = threadIdx.x;
  const int wave = tid >> 6, lane = tid & 63;
  const int lr = lane & 15, quad = lane >> 4;
  const int wm = (wave & 1) << 6, wn = (wave >> 1) << 6;
  const int m0 = blockIdx.y << 7, n0 = blockIdx.x << 7;

  f32x4 acc[4][4] = {};
  for (int k0 = 0; k0 < K; k0 += 32) {
    __syncthreads();
#pragma unroll
    for (int i = 0; i < 2; ++i) {
      const int ch = tid + (i << 8);
      const int row = ch >> 2, col = (ch & 3) << 3;
      GLOAD_LDS16(A + (size_t)(m0 + row) * K + k0 + col, As + ch * 8);
      GLOAD_LDS16(W + (size_t)(n0 + row) * K + k0 + col, Bs + ch * 8);
    }
    __syncthreads();
    bf16x8 afr[4], bfr[4];
#pragma unroll
    for (int mi = 0; mi < 4; ++mi)
      afr[mi] = *(const bf16x8*)&As[(wm + mi * 16 + lr) * 32 + quad * 8];
#pragma unroll
    for (int ni = 0; ni < 4; ++ni)
      bfr[ni] = *(const bf16x8*)&Bs[(wn + ni * 16 + lr) * 32 + quad * 8];
#pragma unroll
    for (int mi = 0; mi < 4; ++mi)
#pragma unroll
      for (int ni = 0; ni < 4; ++ni)
        acc[mi][ni] = MFMA_BF16(afr[mi], bfr[ni], acc[mi][ni]);
  }
#pragma unroll
  for (int mi = 0; mi < 4; ++mi)
#pragma unroll
    for (int ni = 0; ni < 4; ++ni) {
      const int col = n0 + wn + ni * 16 + lr;
      const float bc = bias[col];
      const f32x4 v = acc[mi][ni];
#pragma unroll
      for (int r = 0; r < 4; ++r) {
        const int row = m0 + wm + mi * 16 + (quad << 2) + r;
        out[(size_t)row * kDim + col] = v[r] + bc;
      }
    }
}

// ---------------------------------------------------------------------------
// Fused attention r7: one WG = 4 waves = 64 q-rows of one (b,h); single pass
// over kv in 64-chunks. K/V chunk staged via async global_load_lds into
// XOR-swizzled LDS (16B chunk c of row r stored at slot c^(r&7) -> all frag
// ds_read_b128 are <=2-way). P never touches LDS: QK^T D[kv][q] -> exp in
// regs -> shuffle transpose (8 shfl + 4 sel per 32 kv) -> PV A-frag.
// L = row-sum accumulated as scalar during exp (no ones-MFMA), reduced with
// 2 shfl_xor at the end. XCD clustering: 16 WGs of a head share bid%8.
// ---------------------------------------------------------------------------
__global__ __launch_bounds__(256, 4) void attn_fused(const __bf16* __restrict__ Qb,
                                                     const __bf16* __restrict__ Kb,
                                                     const __bf16* __restrict__ Vb,
                                                     const float* __restrict__ rel,
                                                     __bf16* __restrict__ AO) {
  __shared__ __bf16 Klds[64 * 64];  // 8 KB: [kv64][d64], swizzled
  __shared__ __bf16 Vlds[64 * 64];  // 8 KB: [d64][kv64], swizzled
  const int tid = threadIdx.x;
  const int wave = tid >> 6, lane = tid & 63;
  const int lr = lane & 15, quad = lane >> 4;
  // XCD clustering: x=bid&7, g=bid>>3; head = x + 8*(g&7); qblk = g>>3.
  const int x = blockIdx.x & 7, g = blockIdx.x >> 3;
  const int hg = x + ((g & 7) << 3);
  const int b = hg >> 4, h = hg & 15, q0 = (g >> 3) << 6;
  const __bf16* Qh = Qb + ((size_t)hg << 16);  // [n][64]
  const __bf16* Kh = Kb + ((size_t)hg << 16);  // [n][64] (r folded)
  const __bf16* Vh = Vb + ((size_t)hg << 16);  // [64][n] (r folded)
  const float* rb = rel + (b << 10);

  // Q as B-fragments for this wave's q-tile: B[n=q=lane&15][k=quad*8+j]
  const __bf16* qrow = Qh + (q0 + (wave << 4) + lr) * 64 + (quad << 3);
  const bf16x8 qf0 = *(const bf16x8*)qrow;
  const bf16x8 qf1 = *(const bf16x8*)(qrow + 32);

  f32x4 accO[4] = {{0.f, 0.f, 0.f, 0.f}, {0.f, 0.f, 0.f, 0.f},
                   {0.f, 0.f, 0.f, 0.f}, {0.f, 0.f, 0.f, 0.f}};
  float Lp = 0.f;
  const int xk = lr & 7;

  for (int it = 0; it < 16; ++it) {
    const int kv0 = it << 6;
    __syncthreads();  // prior compute done before overwrite
#pragma unroll
    for (int half = 0; half < 2; ++half) {
      const int idx = tid + (half << 8);
      const int row = idx >> 3, c = idx & 7;
      const int gc = (c ^ (row & 7)) << 3;  // swizzled global 16B chunk
      GLOAD_LDS16(Kh + (size_t)(kv0 + row) * 64 + gc, Klds + idx * 8);
      GLOAD_LDS16(Vh + (size_t)row * kNKV + kv0 + gc, Vlds + idx * 8);
    }
    __syncthreads();  // drains vmcnt -> staged data visible

#pragma unroll
    for (int s = 0; s < 2; ++s) {  // two 32-kv sub-chunks
      int tt[2][2];                // [tile-half][01/23] packed bf16x2
#pragma unroll
      for (int half = 0; half < 2; ++half) {
        const int kvt = (s << 1) + half;
        const int kr = ((kvt << 4) + lr) << 6;
        const bf16x8 ka0 = *(const bf16x8*)&Klds[kr + ((quad ^ xk) << 3)];
        const bf16x8 ka1 = *(const bf16x8*)&Klds[kr + (((4 + quad) ^ xk) << 3)];
        f32x4 d = {0.f, 0.f, 0.f, 0.f};
        d = MFMA_BF16(ka0, qf0, d);
        d = MFMA_BF16(ka1, qf1, d);  // D[kv=quad*4+r][q=lr]
        const f32x4 rcv = *(const f32x4*)(rb + kv0 + (kvt << 4) + (quad << 2));
        const float p0 = fmaxf(rcv[0], 1e-6f) * __expf(d[0] * 0.125f);
        const float p1 = fmaxf(rcv[1], 1e-6f) * __expf(d[1] * 0.125f);
        const float p2 = fmaxf(rcv[2], 1e-6f) * __expf(d[2] * 0.125f);
        const float p3 = fmaxf(rcv[3], 1e-6f) * __expf(d[3] * 0.125f);
        Lp += (p0 + p1) + (p2 + p3);
        bf16x2 lo2 = {(__bf16)p0, (__bf16)p1};
        bf16x2 hi2 = {(__bf16)p2, (__bf16)p3};
        tt[half][0] = __builtin_bit_cast(int, lo2);
        tt[half][1] = __builtin_bit_cast(int, hi2);
      }
      // Shuffle transpose: target (quad,lr) A-frag A[q=lr][kv=quad*8+j].
      const int base = ((quad & 1) << 5) + lr;  // src lane qs*16+lr, qs=(quad&1)*2
      const int r0a = __shfl(tt[0][0], base, 64), r0b = __shfl(tt[1][0], base, 64);
      const int r1a = __shfl(tt[0][1], base, 64), r1b = __shfl(tt[1][1], base, 64);
      const int r2a = __shfl(tt[0][0], base + 16, 64), r2b = __shfl(tt[1][0], base + 16, 64);
      const int r3a = __shfl(tt[0][1], base + 16, 64), r3b = __shfl(tt[1][1], base + 16, 64);
      const bool loq = quad < 2;  // tile T = quad>>1
      int4 ai;
      ai.x = loq ? r0a : r0b;
      ai.y = loq ? r1a : r1b;
      ai.z = loq ? r2a : r2b;
      ai.w = loq ? r3a : r3b;
      const bf16x8 pa = __builtin_bit_cast(bf16x8, ai);
      // PV: B[n=d=lane&15][k=kv] from swizzled Vlds
#pragma unroll
      for (int dt = 0; dt < 4; ++dt) {
        const bf16x8 vb = *(const bf16x8*)&Vlds[(((dt << 4) + lr) << 6) +
                                                ((((s << 2) + quad) ^ xk) << 3)];
        accO[dt] = MFMA_BF16(pa, vb, accO[dt]);
      }
    }
  }

  // L: sum across quads (all lanes with same lr end with full row-sum).
  Lp += __shfl_xor(Lp, 16, 64);
  Lp += __shfl_xor(Lp, 32, 64);
  float linv[4];
#pragma unroll
  for (int r = 0; r < 4; ++r)
    linv[r] = 1.f / __shfl(Lp, (quad << 2) + r, 64);  // L[q=quad*4+r]

  // D[q=quad*4+r][d=dt*16+lr] -> AO[b*1024+q][h*64+d]
#pragma unroll
  for (int dt = 0; dt < 4; ++dt) {
    const int dcol = (h << 6) + (dt << 4) + lr;
#pragma unroll
    for (int r = 0; r < 4; ++r) {
      const int qg = q0 + (wave << 4) + (quad << 2) + r;
      AO[((size_t)(b << 10) + qg) * kDim + dcol] = (__bf16)(accO[dt][r] * linv[r]);
    }
  }
}

extern "C" void kernel_launch(void* const* d_in, const int* in_sizes, int n_in,
                              void* d_out, int out_size, void* d_ws, size_t ws_size,
                              hipStream_t stream) {
  (void)in_sizes; (void)n_in; (void)out_size; (void)ws_size;
  const float* qf  = (const float*)d_in[0];
  const float* kvf = (const float*)d_in[1];
  const float* rel = (const float*)d_in[2];
  const float* Wq  = (const float*)d_in[3];
  const float* bq  = (const float*)d_in[4];
  const float* Wk  = (const float*)d_in[5];
  const float* bk  = (const float*)d_in[6];
  const float* Wv  = (const float*)d_in[7];
  const float* bv  = (const float*)d_in[8];
  const float* Wo  = (const float*)d_in[9];
  const float* bo  = (const float*)d_in[10];

  const size_t big = (size_t)kB * 1024 * kDim;  // 4M elements
  __bf16* p = (__bf16*)d_ws;
  __bf16* cqf  = p; p += big;
  __bf16* ckvf = p; p += big;
  __bf16* cWq  = p; p += kDim * kDim;
  __bf16* cWk  = p; p += kDim * kDim;
  __bf16* cWv  = p; p += kDim * kDim;
  __bf16* cWo  = p; p += kDim * kDim;
  __bf16* q_buf  = p; p += big;
  __bf16* k_buf  = p; p += big;
  __bf16* vT_buf = p; p += big;
  __bf16* ao_buf = p; p += big;

  Conv6 cv;
  const float* srcs[6] = {qf, kvf, Wq, Wk, Wv, Wo};
  __bf16* dsts[6] = {cqf, ckvf, cWq, cWk, cWv, cWo};
  const int n4s[6] = {(int)(big >> 2), (int)(big >> 2),
                      kDim * kDim / 4, kDim * kDim / 4, kDim * kDim / 4, kDim * kDim / 4};
  for (int i = 0; i < 6; ++i) { cv.src[i] = srcs[i]; cv.dst[i] = dsts[i]; cv.n4[i] = n4s[i]; }
  convert6<<<dim3(256, 6), 256, 0, stream>>>(cv);

  QKVArgs qa;
  qa.A[0] = cqf;  qa.A[1] = ckvf; qa.A[2] = ckvf;
  qa.W[0] = cWq;  qa.W[1] = cWk;  qa.W[2] = cWv;
  qa.bias[0] = bq; qa.bias[1] = bk; qa.bias[2] = bv;
  qa.rel = rel;
  qa.out[0] = q_buf; qa.out[1] = k_buf; qa.out[2] = vT_buf;
  qkv_gemm<<<dim3(kDim / 128, (kB * 1024) / 128, 3), 256, 0, stream>>>(qa);

  attn_fused<<<kB * kHeads * (1024 / 64), 256, 0, stream>>>(q_buf, k_buf, vT_buf, rel, ao_buf);

  o_gemm<<<dim3(kDim / 128, (kB * 1024) / 128), 256, 0, stream>>>(ao_buf, cWo, bo, (float*)d_out);
}

// Round 8
// 218.588 us; speedup vs baseline: 1.1502x; 1.0237x over previous
//
#include <hip/hip_runtime.h>
#include <hip/hip_bf16.h>

typedef __bf16 bf16x8 __attribute__((ext_vector_type(8)));
typedef __bf16 bf16x4 __attribute__((ext_vector_type(4)));
typedef __bf16 bf16x2 __attribute__((ext_vector_type(2)));
typedef float  f32x4  __attribute__((ext_vector_type(4)));

#define MFMA_BF16(a, b, c) __builtin_amdgcn_mfma_f32_16x16x32_bf16((a), (b), (c), 0, 0, 0)

#define GLOAD_LDS16(g, l)                                          \
  __builtin_amdgcn_global_load_lds(                                \
      (const __attribute__((address_space(1))) void*)(g),          \
      (__attribute__((address_space(3))) void*)(l), 16, 0, 0)

static constexpr int kDim = 1024;
static constexpr int kHeads = 16;
static constexpr int kB = 4;
static constexpr int kNKV = 1024;

// ---------------------------------------------------------------------------
// fp32 -> bf16 canonicalization (fp32 inputs confirmed r1/r2).
// ---------------------------------------------------------------------------
struct Conv6 {
  const float* src[6];
  __bf16* dst[6];
  int n4[6];
};
__global__ __launch_bounds__(256) void convert6(Conv6 a) {
  const int w = blockIdx.y;
  const float4* __restrict__ s = (const float4*)a.src[w];
  __bf16* __restrict__ d = a.dst[w];
  const int n4 = a.n4[w];
  const int stride = gridDim.x * blockDim.x;
  for (int i = blockIdx.x * blockDim.x + threadIdx.x; i < n4; i += stride) {
    const float4 v = s[i];
    bf16x4 o = {(__bf16)v.x, (__bf16)v.y, (__bf16)v.z, (__bf16)v.w};
    *(bf16x4*)(d + (size_t)i * 4) = o;
  }
}

// ---------------------------------------------------------------------------
// QKV NT-GEMM r8: BK=64 (16+1 barriers vs 33), XOR-swizzled staging (frag
// ds_read_b128 2-way instead of 16-way at 128B row stride), XCD clustering:
// 1-D grid, XCD x=bid&7 owns m-slabs 4x..4x+3 for ALL (z,n) -> A-slabs stay
// resident in that XCD's L2; z slowest -> W 2MB/phase, kvf reused z=1->2.
// Epilogue (Ct stride-136 stage + coalesced 16B stores) unchanged from r6.
// ---------------------------------------------------------------------------
struct QKVArgs {
  const __bf16* A[3];
  const __bf16* W[3];
  const float* bias[3];
  const float* rel;
  __bf16* out[3];
};

__global__ __launch_bounds__(256) void qkv_gemm(QKVArgs args) {
  constexpr int K = kDim;
  constexpr int CT_STRIDE = 136;
  __shared__ __bf16 As[128 * 64];
  __shared__ __bf16 Bs[128 * 64];
  __shared__ __bf16 Ct[128 * CT_STRIDE];  // 66 KB total LDS
  const int bid = blockIdx.x;
  const int x = bid & 7, t = bid >> 3;
  const int z = t >> 5, j = t & 31;                 // z slowest: Q, K, V phases
  const int m_blk = (x << 2) + (j >> 3), n_blk = j & 7;
  const int m0 = m_blk << 7, n0 = n_blk << 7;
  const int bb = m_blk >> 3;
  const __bf16* __restrict__ A = args.A[z];
  const __bf16* __restrict__ W = args.W[z];
  const float* __restrict__ bias = args.bias[z];
  const float* __restrict__ rel = args.rel;
  __bf16* __restrict__ out = args.out[z];

  const int tid = threadIdx.x;
  const int wave = tid >> 6, lane = tid & 63;
  const int lr = lane & 15, quad = lane >> 4;
  const int wm = (wave & 1) << 6, wn = (wave >> 1) << 6;

  f32x4 acc[4][4] = {};

  for (int k0 = 0; k0 < K; k0 += 64) {
    __syncthreads();
#pragma unroll
    for (int i = 0; i < 4; ++i) {
      const int sc = tid + (i << 8);            // 1024 16B chunks per tile
      const int row = sc >> 3, cp = sc & 7;
      const int gcol = (cp ^ (row & 7)) << 3;   // permute SOURCE col per chunk
      GLOAD_LDS16(A + (size_t)(m0 + row) * K + k0 + gcol, As + sc * 8);
      GLOAD_LDS16(W + (size_t)(n0 + row) * K + k0 + gcol, Bs + sc * 8);
    }
    __syncthreads();
#pragma unroll
    for (int kk = 0; kk < 2; ++kk) {
      bf16x8 afr[4], bfr[4];
#pragma unroll
      for (int mi = 0; mi < 4; ++mi) {
        const int row = wm + mi * 16 + lr;
        afr[mi] = *(const bf16x8*)&As[(row << 6) +
                                      ((((kk << 2) + quad) ^ (row & 7)) << 3)];
      }
#pragma unroll
      for (int ni = 0; ni < 4; ++ni) {
        const int row = wn + ni * 16 + lr;
        bfr[ni] = *(const bf16x8*)&Bs[(row << 6) +
                                      ((((kk << 2) + quad) ^ (row & 7)) << 3)];
      }
#pragma unroll
      for (int mi = 0; mi < 4; ++mi)
#pragma unroll
        for (int ni = 0; ni < 4; ++ni)
          acc[mi][ni] = MFMA_BF16(afr[mi], bfr[ni], acc[mi][ni]);
    }
  }

  // Epilogue: D layout row=(lane>>4)*4+r, col=lane&15 (verified).
#pragma unroll
  for (int mi = 0; mi < 4; ++mi)
#pragma unroll
    for (int ni = 0; ni < 4; ++ni) {
      const int col_l = wn + ni * 16 + lr;
      const float bc = bias[n0 + col_l];
      const f32x4 v = acc[mi][ni];
      const int row0 = wm + mi * 16 + (quad << 2);
      if (z == 2) {
        const f32x4 r4 = *(const f32x4*)(rel + (bb << 10) + ((m0 + row0) & 1023));
        bf16x4 pk;
#pragma unroll
        for (int r = 0; r < 4; ++r) pk[r] = (__bf16)((v[r] + bc) * r4[r]);
        *(bf16x4*)&Ct[col_l * CT_STRIDE + row0] = pk;
      } else if (z == 1) {
        const f32x4 r4 = *(const f32x4*)(rel + (bb << 10) + ((m0 + row0) & 1023));
#pragma unroll
        for (int r = 0; r < 4; ++r)
          Ct[(row0 + r) * CT_STRIDE + col_l] = (__bf16)((v[r] + bc) * r4[r]);
      } else {
#pragma unroll
        for (int r = 0; r < 4; ++r)
          Ct[(row0 + r) * CT_STRIDE + col_l] = (__bf16)(v[r] + bc);
      }
    }
  __syncthreads();

  const int hh0 = n0 >> 6;
  if (z == 2) {
#pragma unroll
    for (int jj = 0; jj < 8; ++jj) {
      const int idx = (jj << 8) + tid;
      const int c = idx >> 4, r8 = (idx & 15) << 3;
      const bf16x8 vv = *(const bf16x8*)&Ct[c * CT_STRIDE + r8];
      const int col = n0 + c;
      const int hh = col >> 6, dd = col & 63;
      *(bf16x8*)(out + ((size_t)(bb * kHeads + hh) * 64 + dd) * 1024 +
                 (m0 & 1023) + r8) = vv;
    }
  } else {
#pragma unroll
    for (int jj = 0; jj < 8; ++jj) {
      const int idx = (jj << 8) + tid;
      const int r = idx >> 4, c8 = (idx & 15) << 3;
      const bf16x8 vv = *(const bf16x8*)&Ct[r * CT_STRIDE + c8];
      const int hh = hh0 + (c8 >> 6), dd = c8 & 63;
      *(bf16x8*)(out + ((size_t)(bb * kHeads + hh) << 16) +
                 (size_t)((m0 & 1023) + r) * 64 + dd) = vv;
    }
  }
}

// ---------------------------------------------------------------------------
// O-projection r8: same BK=64 + swizzled staging + XCD clustering; fp32
// direct stores (64B segments per quad) unchanged.
// ---------------------------------------------------------------------------
__global__ __launch_bounds__(256) void o_gemm(const __bf16* __restrict__ A,
                                              const __bf16* __restrict__ W,
                                              const float* __restrict__ bias,
                                              float* __restrict__ out) {
  constexpr int K = kDim;
  __shared__ __bf16 As[128 * 64];
  __shared__ __bf16 Bs[128 * 64];
  const int bid = blockIdx.x;
  const int x = bid & 7, t = bid >> 3;
  const int m_blk = (x << 2) + (t & 3), n_blk = t >> 2;
  const int m0 = m_blk << 7, n0 = n_blk << 7;
  const int tid = threadIdx.x;
  const int wave = tid >> 6, lane = tid & 63;
  const int lr = lane & 15, quad = lane >> 4;
  const int wm = (wave & 1) << 6, wn = (wave >> 1) << 6;

  f32x4 acc[4][4] = {};
  for (int k0 = 0; k0 < K; k0 += 64) {
    __syncthreads();
#pragma unroll
    for (int i = 0; i < 4; ++i) {
      const int sc = tid + (i << 8);
      const int row = sc >> 3, cp = sc & 7;
      const int gcol = (cp ^ (row & 7)) << 3;
      GLOAD_LDS16(A + (size_t)(m0 + row) * K + k0 + gcol, As + sc * 8);
      GLOAD_LDS16(W + (size_t)(n0 + row) * K + k0 + gcol, Bs + sc * 8);
    }
    __syncthreads();
#pragma unroll
    for (int kk = 0; kk < 2; ++kk) {
      bf16x8 afr[4], bfr[4];
#pragma unroll
      for (int mi = 0; mi < 4; ++mi) {
        const int row = wm + mi * 16 + lr;
        afr[mi] = *(const bf16x8*)&As[(row << 6) +
                                      ((((kk << 2) + quad) ^ (row & 7)) << 3)];
      }
#pragma unroll
      for (int ni = 0; ni < 4; ++ni) {
        const int row = wn + ni * 16 + lr;
        bfr[ni] = *(const bf16x8*)&Bs[(row << 6) +
                                      ((((kk << 2) + quad) ^ (row & 7)) << 3)];
      }
#pragma unroll
      for (int mi = 0; mi < 4; ++mi)
#pragma unroll
        for (int ni = 0; ni < 4; ++ni)
          acc[mi][ni] = MFMA_BF16(afr[mi], bfr[ni], acc[mi][ni]);
    }
  }
#pragma unroll
  for (int mi = 0; mi < 4; ++mi)
#pragma unroll
    for (int ni = 0; ni < 4; ++ni) {
      const int col = n0 + wn + ni * 16 + lr;
      const float bc = bias[col];
      const f32x4 v = acc[mi][ni];
#pragma unroll
      for (int r = 0; r < 4; ++r) {
        const int row = m0 + wm + mi * 16 + (quad << 2) + r;
        out[(size_t)row * kDim + col] = v[r] + bc;
      }
    }
}

// ---------------------------------------------------------------------------
// Fused attention (byte-identical to r7 — 224us round's winner).
// ---------------------------------------------------------------------------
__global__ __launch_bounds__(256, 4) void attn_fused(const __bf16* __restrict__ Qb,
                                                     const __bf16* __restrict__ Kb,
                                                     const __bf16* __restrict__ Vb,
                                                     const float* __restrict__ rel,
                                                     __bf16* __restrict__ AO) {
  __shared__ __bf16 Klds[64 * 64];
  __shared__ __bf16 Vlds[64 * 64];
  const int tid = threadIdx.x;
  const int wave = tid >> 6, lane = tid & 63;
  const int lr = lane & 15, quad = lane >> 4;
  const int x = blockIdx.x & 7, g = blockIdx.x >> 3;
  const int hg = x + ((g & 7) << 3);
  const int b = hg >> 4, h = hg & 15, q0 = (g >> 3) << 6;
  const __bf16* Qh = Qb + ((size_t)hg << 16);
  const __bf16* Kh = Kb + ((size_t)hg << 16);
  const __bf16* Vh = Vb + ((size_t)hg << 16);
  const float* rb = rel + (b << 10);

  const __bf16* qrow = Qh + (q0 + (wave << 4) + lr) * 64 + (quad << 3);
  const bf16x8 qf0 = *(const bf16x8*)qrow;
  const bf16x8 qf1 = *(const bf16x8*)(qrow + 32);

  f32x4 accO[4] = {{0.f, 0.f, 0.f, 0.f}, {0.f, 0.f, 0.f, 0.f},
                   {0.f, 0.f, 0.f, 0.f}, {0.f, 0.f, 0.f, 0.f}};
  float Lp = 0.f;
  const int xk = lr & 7;

  for (int it = 0; it < 16; ++it) {
    const int kv0 = it << 6;
    __syncthreads();
#pragma unroll
    for (int half = 0; half < 2; ++half) {
      const int idx = tid + (half << 8);
      const int row = idx >> 3, c = idx & 7;
      const int gc = (c ^ (row & 7)) << 3;
      GLOAD_LDS16(Kh + (size_t)(kv0 + row) * 64 + gc, Klds + idx * 8);
      GLOAD_LDS16(Vh + (size_t)row * kNKV + kv0 + gc, Vlds + idx * 8);
    }
    __syncthreads();

#pragma unroll
    for (int s = 0; s < 2; ++s) {
      int tt[2][2];
#pragma unroll
      for (int half = 0; half < 2; ++half) {
        const int kvt = (s << 1) + half;
        const int kr = ((kvt << 4) + lr) << 6;
        const bf16x8 ka0 = *(const bf16x8*)&Klds[kr + ((quad ^ xk) << 3)];
        const bf16x8 ka1 = *(const bf16x8*)&Klds[kr + (((4 + quad) ^ xk) << 3)];
        f32x4 d = {0.f, 0.f, 0.f, 0.f};
        d = MFMA_BF16(ka0, qf0, d);
        d = MFMA_BF16(ka1, qf1, d);
        const f32x4 rcv = *(const f32x4*)(rb + kv0 + (kvt << 4) + (quad << 2));
        const float p0 = fmaxf(rcv[0], 1e-6f) * __expf(d[0] * 0.125f);
        const float p1 = fmaxf(rcv[1], 1e-6f) * __expf(d[1] * 0.125f);
        const float p2 = fmaxf(rcv[2], 1e-6f) * __expf(d[2] * 0.125f);
        const float p3 = fmaxf(rcv[3], 1e-6f) * __expf(d[3] * 0.125f);
        Lp += (p0 + p1) + (p2 + p3);
        bf16x2 lo2 = {(__bf16)p0, (__bf16)p1};
        bf16x2 hi2 = {(__bf16)p2, (__bf16)p3};
        tt[half][0] = __builtin_bit_cast(int, lo2);
        tt[half][1] = __builtin_bit_cast(int, hi2);
      }
      const int base = ((quad & 1) << 5) + lr;
      const int r0a = __shfl(tt[0][0], base, 64), r0b = __shfl(tt[1][0], base, 64);
      const int r1a = __shfl(tt[0][1], base, 64), r1b = __shfl(tt[1][1], base, 64);
      const int r2a = __shfl(tt[0][0], base + 16, 64), r2b = __shfl(tt[1][0], base + 16, 64);
      const int r3a = __shfl(tt[0][1], base + 16, 64), r3b = __shfl(tt[1][1], base + 16, 64);
      const bool loq = quad < 2;
      int4 ai;
      ai.x = loq ? r0a : r0b;
      ai.y = loq ? r1a : r1b;
      ai.z = loq ? r2a : r2b;
      ai.w = loq ? r3a : r3b;
      const bf16x8 pa = __builtin_bit_cast(bf16x8, ai);
#pragma unroll
      for (int dt = 0; dt < 4; ++dt) {
        const bf16x8 vb = *(const bf16x8*)&Vlds[(((dt << 4) + lr) << 6) +
                                                ((((s << 2) + quad) ^ xk) << 3)];
        accO[dt] = MFMA_BF16(pa, vb, accO[dt]);
      }
    }
  }

  Lp += __shfl_xor(Lp, 16, 64);
  Lp += __shfl_xor(Lp, 32, 64);
  float linv[4];
#pragma unroll
  for (int r = 0; r < 4; ++r)
    linv[r] = 1.f / __shfl(Lp, (quad << 2) + r, 64);

#pragma unroll
  for (int dt = 0; dt < 4; ++dt) {
    const int dcol = (h << 6) + (dt << 4) + lr;
#pragma unroll
    for (int r = 0; r < 4; ++r) {
      const int qg = q0 + (wave << 4) + (quad << 2) + r;
      AO[((size_t)(b << 10) + qg) * kDim + dcol] = (__bf16)(accO[dt][r] * linv[r]);
    }
  }
}

extern "C" void kernel_launch(void* const* d_in, const int* in_sizes, int n_in,
                              void* d_out, int out_size, void* d_ws, size_t ws_size,
                              hipStream_t stream) {
  (void)in_sizes; (void)n_in; (void)out_size; (void)ws_size;
  const float* qf  = (const float*)d_in[0];
  const float* kvf = (const float*)d_in[1];
  const float* rel = (const float*)d_in[2];
  const float* Wq  = (const float*)d_in[3];
  const float* bq  = (const float*)d_in[4];
  const float* Wk  = (const float*)d_in[5];
  const float* bk  = (const float*)d_in[6];
  const float* Wv  = (const float*)d_in[7];
  const float* bv  = (const float*)d_in[8];
  const float* Wo  = (const float*)d_in[9];
  const float* bo  = (const float*)d_in[10];

  const size_t big = (size_t)kB * 1024 * kDim;  // 4M elements
  __bf16* p = (__bf16*)d_ws;
  __bf16* cqf  = p; p += big;
  __bf16* ckvf = p; p += big;
  __bf16* cWq  = p; p += kDim * kDim;
  __bf16* cWk  = p; p += kDim * kDim;
  __bf16* cWv  = p; p += kDim * kDim;
  __bf16* cWo  = p; p += kDim * kDim;
  __bf16* q_buf  = p; p += big;
  __bf16* k_buf  = p; p += big;
  __bf16* vT_buf = p; p += big;
  __bf16* ao_buf = p; p += big;

  Conv6 cv;
  const float* srcs[6] = {qf, kvf, Wq, Wk, Wv, Wo};
  __bf16* dsts[6] = {cqf, ckvf, cWq, cWk, cWv, cWo};
  const int n4s[6] = {(int)(big >> 2), (int)(big >> 2),
                      kDim * kDim / 4, kDim * kDim / 4, kDim * kDim / 4, kDim * kDim / 4};
  for (int i = 0; i < 6; ++i) { cv.src[i] = srcs[i]; cv.dst[i] = dsts[i]; cv.n4[i] = n4s[i]; }
  convert6<<<dim3(256, 6), 256, 0, stream>>>(cv);

  QKVArgs qa;
  qa.A[0] = cqf;  qa.A[1] = ckvf; qa.A[2] = ckvf;
  qa.W[0] = cWq;  qa.W[1] = cWk;  qa.W[2] = cWv;
  qa.bias[0] = bq; qa.bias[1] = bk; qa.bias[2] = bv;
  qa.rel = rel;
  qa.out[0] = q_buf; qa.out[1] = k_buf; qa.out[2] = vT_buf;
  qkv_gemm<<<768, 256, 0, stream>>>(qa);

  attn_fused<<<kB * kHeads * (1024 / 64), 256, 0, stream>>>(q_buf, k_buf, vT_buf, rel, ao_buf);

  o_gemm<<<256, 256, 0, stream>>>(ao_buf, cWo, bo, (float*)d_out);
}